// Round 1
// baseline (637.660 us; speedup 1.0000x reference)
//
#include <hip/hip_runtime.h>

// Problem dims (fixed by setup_inputs)
#define B_   32
#define C_   64
#define T_   300
#define J_   25
#define K9   9
constexpr int PLANE = T_ * J_;           // 7500
constexpr int BCTJ  = B_ * C_ * PLANE;   // 15,360,000
constexpr float BN_EPS = 1e-5f;
constexpr float BN_N   = (float)(B_ * T_ * J_);  // 240000

// ---------------------------------------------------------------------------
// K0: transpose tcn_w [o][c][kt][1] -> Wt[(c*9+kt)*64 + o]
__global__ __launch_bounds__(256) void wt_kernel(const float* __restrict__ w,
                                                 float* __restrict__ Wt) {
  int idx = blockIdx.x * 256 + threadIdx.x;
  if (idx < C_ * C_ * K9) {
    int o = idx / (C_ * K9);
    int r = idx % (C_ * K9);   // c*9+kt
    Wt[r * C_ + o] = w[idx];
  }
}

// ---------------------------------------------------------------------------
// K1: GCN  y1[b,o,t,k] = sum_c W[o,c] * (sum_j x[b,c,t,j] A[j,k]) + bias[o]
__global__ __launch_bounds__(256) void gcn_kernel(
    const float* __restrict__ x, const float* __restrict__ A,
    const float* __restrict__ W, const float* __restrict__ bias,
    float* __restrict__ y1) {
  __shared__ float As[J_ * J_];
  __shared__ float Ws[C_ * C_];
  __shared__ float Xs[C_ * J_];
  __shared__ float XAs[C_ * J_];
  int bid = blockIdx.x;
  int b = bid / T_, t = bid % T_;
  size_t base = (size_t)b * (C_ * PLANE) + (size_t)t * J_;

  for (int i = threadIdx.x; i < J_ * J_; i += 256) As[i] = A[i];
  for (int i = threadIdx.x; i < C_ * C_; i += 256) Ws[i] = W[i];
  for (int i = threadIdx.x; i < C_ * J_; i += 256) {
    int c = i / J_, j = i % J_;
    Xs[i] = x[base + (size_t)c * PLANE + j];
  }
  __syncthreads();
  for (int i = threadIdx.x; i < C_ * J_; i += 256) {
    int c = i / J_, k = i % J_;
    float s = 0.f;
#pragma unroll
    for (int j = 0; j < J_; ++j) s = fmaf(Xs[c * J_ + j], As[j * J_ + k], s);
    XAs[i] = s;
  }
  __syncthreads();
  for (int i = threadIdx.x; i < C_ * J_; i += 256) {
    int o = i / J_, k = i % J_;
    float s = bias[o];
#pragma unroll
    for (int c = 0; c < C_; ++c) s = fmaf(Ws[o * C_ + c], XAs[c * J_ + k], s);
    y1[base + (size_t)o * PLANE + k] = s;
  }
}

// ---------------------------------------------------------------------------
// K2: per-channel sum / sumsq.  One block per (b,c) plane of 7500 floats.
__global__ __launch_bounds__(256) void stats_kernel(const float* __restrict__ in,
                                                    float* __restrict__ stats) {
  int bc = blockIdx.x;
  int c = bc & (C_ - 1);
  const float4* p4 = (const float4*)(in + (size_t)bc * PLANE);
  float s = 0.f, sq = 0.f;
  for (int i = threadIdx.x; i < PLANE / 4; i += 256) {
    float4 v = p4[i];
    s += v.x + v.y + v.z + v.w;
    sq += v.x * v.x + v.y * v.y + v.z * v.z + v.w * v.w;
  }
#pragma unroll
  for (int off = 32; off > 0; off >>= 1) {
    s += __shfl_down(s, off);
    sq += __shfl_down(sq, off);
  }
  __shared__ float ls[2][4];
  int wave = threadIdx.x >> 6, lane = threadIdx.x & 63;
  if (lane == 0) { ls[0][wave] = s; ls[1][wave] = sq; }
  __syncthreads();
  if (threadIdx.x == 0) {
    float S = ls[0][0] + ls[0][1] + ls[0][2] + ls[0][3];
    float SQ = ls[1][0] + ls[1][1] + ls[1][2] + ls[1][3];
    atomicAdd(&stats[c], S);
    atomicAdd(&stats[C_ + c], SQ);
  }
}

// ---------------------------------------------------------------------------
// K3: finalize BN params: bnp[c]=scale, bnp[64+c]=shift
__global__ void bnparam_kernel(const float* __restrict__ stats,
                               const float* __restrict__ g,
                               const float* __restrict__ b,
                               float* __restrict__ bnp) {
  int c = threadIdx.x;
  if (c < C_) {
    float mean = stats[c] / BN_N;
    float var = stats[C_ + c] / BN_N - mean * mean;
    float inv = rsqrtf(var + BN_EPS);
    float sc = g[c] * inv;
    bnp[c] = sc;
    bnp[C_ + c] = b[c] - mean * sc;
  }
}

// ---------------------------------------------------------------------------
// K4: temporal conv.  z = relu(bn1(y1)); y2[b,o,t,j] = sum_{c,kt} w*z + tcn_b
// block = (b, t-tile of 10). lane owns one (t,j); acc[64] = all out channels.
constexpr int TT = 10;
constexpr int ZROWS = TT + 8;          // 18
constexpr int CCH = 32;                // channel chunk
__global__ __launch_bounds__(256) void tcn_kernel(
    const float* __restrict__ y1, const float* __restrict__ Wt,
    const float* __restrict__ bnp1, const float* __restrict__ tbias,
    float* __restrict__ y2) {
  __shared__ float zs[CCH * ZROWS * J_];   // 32*18*25*4 = 57.6 KB
  int bid = blockIdx.x;
  int b = bid / (T_ / TT), tile = bid % (T_ / TT);
  int t0 = tile * TT;
  int n = threadIdx.x;
  int tl = n / J_, j = n % J_;
  bool active = n < TT * J_;
  if (tl > TT - 1) tl = TT - 1;   // clamp inactive lanes for safe LDS reads
  size_t bbase = (size_t)b * (C_ * PLANE);

  float acc[C_];
#pragma unroll
  for (int i = 0; i < C_; ++i) acc[i] = 0.f;

  for (int cc = 0; cc < C_ / CCH; ++cc) {
    __syncthreads();
    for (int idx = threadIdx.x; idx < CCH * ZROWS * J_; idx += 256) {
      int ci = idx / (ZROWS * J_);
      int rem = idx % (ZROWS * J_);
      int tt = rem / J_, jj = rem % J_;
      int gt = t0 - 4 + tt;
      int c = cc * CCH + ci;
      float z = 0.f;
      if (gt >= 0 && gt < T_) {
        float v = y1[bbase + (size_t)c * PLANE + (size_t)gt * J_ + jj];
        z = fmaxf(fmaf(v, bnp1[c], bnp1[C_ + c]), 0.f);
      }
      zs[idx] = z;
    }
    __syncthreads();
    for (int ci = 0; ci < CCH; ++ci) {
      int c = cc * CCH + ci;
      float zreg[K9];
#pragma unroll
      for (int kt = 0; kt < K9; ++kt)
        zreg[kt] = zs[ci * (ZROWS * J_) + (tl + kt) * J_ + j];
      const float* wp = Wt + (size_t)c * (K9 * C_);   // uniform -> s_load
#pragma unroll
      for (int kt = 0; kt < K9; ++kt) {
#pragma unroll
        for (int oi = 0; oi < C_; ++oi)
          acc[oi] = fmaf(wp[kt * C_ + oi], zreg[kt], acc[oi]);
      }
    }
  }
  if (active) {
    int t = t0 + tl;
    size_t obase = bbase + (size_t)t * J_ + j;
#pragma unroll
    for (int oi = 0; oi < C_; ++oi)
      y2[obase + (size_t)oi * PLANE] = acc[oi] + tbias[oi];
  }
}

// ---------------------------------------------------------------------------
// K5: out = relu(bn2(y2) + x), in place on d_out (y2 lives there)
__global__ __launch_bounds__(256) void final_kernel(float* __restrict__ y2,
                                                    const float* __restrict__ x,
                                                    const float* __restrict__ bnp2) {
  int i = blockIdx.x * 256 + threadIdx.x;
  if (i >= BCTJ / 4) return;
  int c = (i / (PLANE / 4)) & (C_ - 1);
  float sc = bnp2[c], sh = bnp2[C_ + c];
  float4 v = ((const float4*)y2)[i];
  float4 xv = ((const float4*)x)[i];
  v.x = fmaxf(fmaf(v.x, sc, sh) + xv.x, 0.f);
  v.y = fmaxf(fmaf(v.y, sc, sh) + xv.y, 0.f);
  v.z = fmaxf(fmaf(v.z, sc, sh) + xv.z, 0.f);
  v.w = fmaxf(fmaf(v.w, sc, sh) + xv.w, 0.f);
  ((float4*)y2)[i] = v;
}

// ---------------------------------------------------------------------------
extern "C" void kernel_launch(void* const* d_in, const int* in_sizes, int n_in,
                              void* d_out, int out_size, void* d_ws, size_t ws_size,
                              hipStream_t stream) {
  const float* x     = (const float*)d_in[0];
  const float* A     = (const float*)d_in[1];
  const float* gcn_w = (const float*)d_in[2];
  const float* gcn_b = (const float*)d_in[3];
  const float* bn1_g = (const float*)d_in[4];
  const float* bn1_b = (const float*)d_in[5];
  const float* tcn_w = (const float*)d_in[6];
  const float* tcn_b = (const float*)d_in[7];
  const float* bn2_g = (const float*)d_in[8];
  const float* bn2_b = (const float*)d_in[9];
  float* out = (float*)d_out;

  float* y1    = (float*)d_ws;            // 15,360,000 floats
  float* Wt    = y1 + BCTJ;               // 36,864 floats
  float* stats = Wt + C_ * C_ * K9;       // 256 floats: [sum1,sq1,sum2,sq2]
  float* bnp   = stats + 256;             // 256 floats: [sc1,sh1,sc2,sh2]

  hipMemsetAsync(stats, 0, 256 * sizeof(float), stream);
  wt_kernel<<<(C_ * C_ * K9 + 255) / 256, 256, 0, stream>>>(tcn_w, Wt);
  gcn_kernel<<<B_ * T_, 256, 0, stream>>>(x, A, gcn_w, gcn_b, y1);
  stats_kernel<<<B_ * C_, 256, 0, stream>>>(y1, stats);
  bnparam_kernel<<<1, 64, 0, stream>>>(stats, bn1_g, bn1_b, bnp);
  tcn_kernel<<<B_ * (T_ / TT), 256, 0, stream>>>(y1, Wt, bnp, tcn_b, out);
  stats_kernel<<<B_ * C_, 256, 0, stream>>>(out, stats + 128);
  bnparam_kernel<<<1, 64, 0, stream>>>(stats + 128, bn2_g, bn2_b, bnp + 128);
  final_kernel<<<BCTJ / 4 / 256, 256, 0, stream>>>(out, x, bnp + 128);
}